// Round 4
// baseline (409.965 us; speedup 1.0000x reference)
//
#include <hip/hip_runtime.h>

#define HSZ 50        // real hidden units
#define TSZ 512       // timesteps
#define NB  4         // batches per (single-wave) workgroup -> 512 wgs
#define KPAD 96       // hlds row stride in f16 (192 B): rows shift 16 banks -> <=2-way (free)

typedef _Float16 half8  __attribute__((ext_vector_type(8)));
typedef float   floatx4 __attribute__((ext_vector_type(4)));

// Activations on pre-scaled arguments (A rows carry the log2e factors):
//   sigmoid gates: y = -log2e * x  ->  sig = rcp(1 + exp2(y))
//   tanh gate:     y = 2*log2e * x ->  tanh = 1 - 2*rcp(1 + exp2(y))
__device__ __forceinline__ float sig_y(float y) {
    return __builtin_amdgcn_rcpf(1.0f + __builtin_amdgcn_exp2f(y));
}
__device__ __forceinline__ float tanh_y(float y) {
    return fmaf(-2.0f, __builtin_amdgcn_rcpf(1.0f + __builtin_amdgcn_exp2f(y)), 1.0f);
}

// R13: barrier elimination. R11's ~920cy step is ~330cy issue + ~590cy stall;
// R12 proved extra waves can't fill the stall (contention >= fill). The last
// big stall candidate is the 2x/step 4-wave __syncthreads (barrier + waitcnt
// drain + wake skew). This kernel removes it: ONE wave owns the entire cell
// for 4 batches, so the h-exchange is intra-wave (ds_write -> lgkmcnt(0) ->
// ds_read; DS pipe is per-wave in-order, NO s_barrier).
//   A: 208 rows, UNIT-major (row R = 4u+g, gate g = R&3, unit u = R>>2), 13
//      M-tiles of 16, K=64 (52 used: k<50 h, k=50 bias, k=51 x) -> 26 MFMAs.
//      acc[j][r] at lane (n,q) = gate r of unit 4j+q, col n -> one acc quad
//      = all 4 gates of one unit (no gate gather at all).
//   B: cols replicate batches x4 (col n = batch n&3): B-read row n&3 ->
//      16-lane broadcast per address (no mirror writes, ~no conflicts).
//   Cells: lane (n,q), rr=n>>2 owns units u=16m+4rr+q (m=0..2; acc[4m+rr]
//      via 3 cndmasks/value) + rr==0 owns tile-12 extras u=48+q (q<2).
//      u=50 slot: init 1.0, never written. u=51 slot: rr0/q3 lane writes
//      x_{t+1}. 3-4 cells/lane = 15-20 trans, balanced.
__global__ __launch_bounds__(64, 1)
void lstm_1w(const float* __restrict__ x,
             const float* __restrict__ W_ih,
             const float* __restrict__ W_hh,
             const float* __restrict__ b_ih,
             const float* __restrict__ b_hh,
             const float* __restrict__ W_lin,
             const float* __restrict__ b_lin,
             float* __restrict__ out)
{
    __shared__ float xs[TSZ][NB];                         // x^T [t][b]  (8 KB)
    __shared__ __align__(16) _Float16 hlds[2][NB][KPAD];  // aug-h dbuf (1.5 KB)

    const int ln = threadIdx.x;      // single wave: 0..63
    const int n  = ln & 15;          // MFMA column
    const int q  = ln >> 4;          // quad -> k-chunk AND unit low bits
    const int rr = n >> 2;           // replica index (which unit slice this lane owns)
    const int b  = n & 3;            // real batch this lane computes
    const int b0 = blockIdx.x * NB;

    // --- stage x transposed: global [b][t] -> LDS [t][b] ---
    const float* xg = x + (size_t)b0 * TSZ;
    for (int i = ln; i < NB * TSZ; i += 64)
        xs[i & (TSZ - 1)][i >> 9] = xg[i];
    // --- init h buffers: zero except k==50 slot = 1.0 (both buffers) ---
    for (int i = ln; i < 2 * NB * KPAD; i += 64)
        ((_Float16*)hlds)[i] = (i % KPAD == 50) ? (_Float16)1.0f : (_Float16)0.0f;

    // --- A fragments: tile j rows R=16j+n -> unit 4j+(n>>2), gate n&3.
    //     k<50 -> W_hh ; k==50 -> b_ih+b_hh ; k==51 -> W_ih ; else 0.
    //     Pre-scaled: gates i,f,o -> -log2e ; gate g -> +2*log2e.
    half8 af[13][2];
    {
        const int g  = n & 3;
        const int ub = n >> 2;
        const float gs = (g == 2) ? 2.88539008f : -1.44269504f;
#pragma unroll
        for (int j = 0; j < 13; ++j) {
            const int u = 4 * j + ub;
            const int wrow = g * HSZ + u;
            const bool ok = (u < HSZ);
#pragma unroll
            for (int kt = 0; kt < 2; ++kt) {
#pragma unroll
                for (int jj = 0; jj < 8; ++jj) {
                    const int k = kt * 32 + q * 8 + jj;
                    float v = 0.0f;
                    if (ok) {
                        if (k < HSZ)      v = W_hh[wrow * HSZ + k];
                        else if (k == 50) v = b_ih[wrow] + b_hh[wrow];
                        else if (k == 51) v = W_ih[wrow];
                    }
                    af[j][kt][jj] = (_Float16)(v * gs);
                }
            }
        }
    }

    float c0 = 0.0f, c1 = 0.0f, c2 = 0.0f, c3 = 0.0f;  // cell states (per-lane units)
    __syncthreads();                 // 1-wave block: cheap; staging visible
    if (ln < NB) hlds[0][ln][51] = (_Float16)xs[0][ln];
    __syncthreads();

    const floatx4 zero4 = {0.0f, 0.0f, 0.0f, 0.0f};

#pragma unroll 2
    for (int t = 0; t < TSZ; ++t) {
        const int rb = t & 1, wb = rb ^ 1;

        // B fragments: broadcast reads (16 lanes share each address).
        const half8 bf0 = *(const half8*)&hlds[rb][b][q * 8];
        const half8 bf1 = *(const half8*)&hlds[rb][b][32 + q * 8];
        const float xnext = xs[(t + 1) & (TSZ - 1)][b];

        floatx4 acc[13];
#pragma unroll
        for (int j = 0; j < 13; ++j) {
            acc[j] = __builtin_amdgcn_mfma_f32_16x16x32_f16(af[j][0], bf0, zero4,  0, 0, 0);
            acc[j] = __builtin_amdgcn_mfma_f32_16x16x32_f16(af[j][1], bf1, acc[j], 0, 0, 0);
        }

        _Float16* const hw = &hlds[wb][b][0];

        // cells m=0..2: u = 16m + 4rr + q ; gates = acc[4m+rr][0..3]
#define CELL_M(MI, CV)                                                         \
        {                                                                      \
            const floatx4 t0 = (rr & 1) ? acc[4*MI+1] : acc[4*MI+0];           \
            const floatx4 t1 = (rr & 1) ? acc[4*MI+3] : acc[4*MI+2];           \
            const floatx4 pr = (rr & 2) ? t1 : t0;                             \
            const float i_ = sig_y (pr[0]);                                    \
            const float f_ = sig_y (pr[1]);                                    \
            const float g_ = tanh_y(pr[2]);                                    \
            const float o_ = sig_y (pr[3]);                                    \
            CV = fmaf(f_, CV, i_ * g_);                                        \
            const float h_ = o_ * tanh_y(CV * 2.88539008f);                    \
            hw[16 * MI + 4 * rr + q] = (_Float16)h_;                           \
        }
        CELL_M(0, c0)
        CELL_M(1, c1)
        CELL_M(2, c2)
#undef CELL_M

        // tile 12: u = 48+q (real for q<2); rr==0 lanes own; q==3 writes x-aug.
        {
            const floatx4 pr = acc[12];
            const float i_ = sig_y (pr[0]);
            const float f_ = sig_y (pr[1]);
            const float g_ = tanh_y(pr[2]);
            const float o_ = sig_y (pr[3]);
            c3 = fmaf(f_, c3, i_ * g_);
            const float h_ = o_ * tanh_y(c3 * 2.88539008f);
            if (rr == 0) {
                if (q < 2)  hw[48 + q] = (_Float16)h_;
                if (q == 3) hw[51] = (_Float16)xnext;
            }
        }

        // Intra-wave exchange: writes must land before next step's reads.
        // DS pipe is in-order per wave; lgkmcnt(0) is the cheap guarantee.
        asm volatile("s_waitcnt lgkmcnt(0)" ::: "memory");
    }

    // --- epilogue: out[b0+b] = b_lin + sum_u h_T[u]*W_lin[u]; TSZ even -> buf 0
    if (ln < NB) {
        float accv = b_lin[0];
        for (int u = 0; u < HSZ; ++u)
            accv = fmaf((float)hlds[0][ln][u], W_lin[u], accv);
        out[(size_t)b0 + ln] = accv;
    }
}

extern "C" void kernel_launch(void* const* d_in, const int* in_sizes, int n_in,
                              void* d_out, int out_size, void* d_ws, size_t ws_size,
                              hipStream_t stream) {
    const float* x     = (const float*)d_in[0];
    const float* W_ih  = (const float*)d_in[1];
    const float* W_hh  = (const float*)d_in[2];
    const float* b_ih  = (const float*)d_in[3];
    const float* b_hh  = (const float*)d_in[4];
    const float* W_lin = (const float*)d_in[5];
    const float* b_lin = (const float*)d_in[6];
    float* outp = (float*)d_out;

    const int B = in_sizes[0] / TSZ;   // 2048 -> 512 single-wave workgroups
    hipLaunchKernelGGL(lstm_1w, dim3(B / NB), dim3(64), 0, stream,
                       x, W_ih, W_hh, b_ih, b_hh, W_lin, b_lin, outp);
}

// Round 5
// 228.694 us; speedup vs baseline: 1.7926x; 1.7926x over previous
//
#include <hip/hip_runtime.h>

#define HSZ 50        // real hidden units
#define TSZ 512       // timesteps
#define NB  8         // batches per workgroup -> 256 wgs (1 per CU)
#define KPAD 72       // hlds row stride in f16 (144 B, 16B-aligned)

typedef _Float16 half8  __attribute__((ext_vector_type(8)));
typedef float   floatx4 __attribute__((ext_vector_type(4)));

// Activations on pre-scaled arguments (A rows carry the log2e factors):
//   sigmoid gates: y = -log2e * x  ->  sig = rcp(1 + exp2(y))
//   tanh gate:     y = 2*log2e * x ->  tanh = 1 - 2*rcp(1 + exp2(y))
// Robust at extremes: exp2->inf => rcp->0 ; exp2->0 => rcp(1)=1.
__device__ __forceinline__ float sig_y(float y) {
    return __builtin_amdgcn_rcpf(1.0f + __builtin_amdgcn_exp2f(y));
}
__device__ __forceinline__ float tanh_y(float y) {
    return fmaf(-2.0f, __builtin_amdgcn_rcpf(1.0f + __builtin_amdgcn_exp2f(y)), 1.0f);
}

// R14: latency-trim pass on R11 (the 920cy/step champion). Period model
// (validated vs counters): issue ~550 (MFMA 128 + trans 160 + VALU ~260)
// + exposed latency ~330 (read 110, mfma tail 70, drain+barrier 150).
// Trims: (1) per-cell b16 h-writes issued as soon as each cell finishes
// (cell0's write latency hides under cell1's trans chain -> smaller
// pre-barrier lgkm drain); (2) branchless xnext on all waves (kills the
// wave-3 branch skew at the barrier); (3) waves_per_eu(1,1): 1 wave/SIMD
// anyway, give the allocator the full register file for scheduling.
// Kept: K-augmentation (bias k=50, x_t k=51 -> zero C-input), x2 mirror
// cols (selection from own registers), pre-scaled A (exp2-ready output),
// 1 barrier/step, f16 h exchange.
__global__ __launch_bounds__(256) __attribute__((amdgpu_waves_per_eu(1, 1)))
void lstm_trim(const float* __restrict__ x,
               const float* __restrict__ W_ih,
               const float* __restrict__ W_hh,
               const float* __restrict__ b_ih,
               const float* __restrict__ b_hh,
               const float* __restrict__ W_lin,
               const float* __restrict__ b_lin,
               float* __restrict__ out)
{
    __shared__ float xs[TSZ][NB];                         // x^T [t][n]  (16 KB)
    __shared__ __align__(16) _Float16 hlds[2][16][KPAD];  // aug-h^T dbuf (4.5 KB)

    const int tid = threadIdx.x;
    const int w   = tid >> 6;        // wave id 0..3 -> unit group [16w,16w+16)
    const int ln  = tid & 63;        // lane
    const int n   = ln & 15;         // MFMA column
    const int q   = ln >> 4;         // quad
    const int hi  = (n >> 3) & 1;    // 0: units 4q..4q+1, 1: units 4q+2..4q+3
    const int nb  = n & 7;           // real batch this lane activates
    const int b0  = blockIdx.x * NB;

    // --- stage x transposed: global [b][t] -> LDS [t][b] (coalesced) ---
    const float* xg = x + (size_t)b0 * TSZ;
    for (int i = tid; i < NB * TSZ; i += 256)
        xs[i & (TSZ - 1)][i >> 9] = xg[i];
    // --- init h buffers: zero except k==50 slot = 1.0 (both buffers) ---
    for (int i = tid; i < 2 * 16 * KPAD; i += 256)
        ((_Float16*)hlds)[i] = (i % KPAD == 50) ? (_Float16)1.0f : (_Float16)0.0f;

    // --- A fragments: lane holds A[m=16w+n][k=kt*32+q*8+j], augmented and
    //     pre-scaled: k<50 -> W_hh ; k==50 -> b_ih+b_hh ; k==51 -> W_ih.
    //     Row scale: gates i,f,o -> -log2e ; gate g -> +2*log2e.
    const int uA = 16 * w + n;
    half8 af[4][2];
#pragma unroll
    for (int g = 0; g < 4; ++g) {
        const float gs = (g == 2) ? 2.88539008f : -1.44269504f;
        const int row = g * HSZ + uA;
        const bool rok = (uA < HSZ);
#pragma unroll
        for (int kt = 0; kt < 2; ++kt) {
#pragma unroll
            for (int j = 0; j < 8; ++j) {
                const int k = kt * 32 + q * 8 + j;
                float v = 0.0f;
                if (rok) {
                    if (k < HSZ)      v = W_hh[row * HSZ + k];
                    else if (k == 50) v = b_ih[row] + b_hh[row];
                    else if (k == 51) v = W_ih[row];
                }
                af[g][kt][j] = (_Float16)(v * gs);
            }
        }
    }

    float c0 = 0.0f, c1 = 0.0f;      // lane-local cell states (2 units, batch nb)
    __syncthreads();                 // xs + hlds base fill ready
    if (tid < 16)                    // x_0 into buffer 0's aug slot, both halves
        hlds[0][tid][51] = (_Float16)xs[0][tid & 7];
    __syncthreads();

    const floatx4 zero4 = {0.0f, 0.0f, 0.0f, 0.0f};
    // h destination: row nb (+ mirror nb+8), cols 16w+4q+2*hi .. +1
    const int kcol = 16 * w + 4 * q + 2 * hi;
    _Float16* const hwp0 = &hlds[0][nb][kcol];
    _Float16* const hwp1 = &hlds[1][nb][kcol];
    const bool xlane = (w == 3) && (q == 0) && (hi == 1);  // units 50,51

#pragma unroll 2
    for (int t = 0; t < TSZ; ++t) {
        const int rb = t & 1, wb = rb ^ 1;

        // B fragments: hlds[rb][n][k-contiguous]; cols 8..15 mirror cols 0..7
        const half8 bf0 = *(const half8*)&hlds[rb][n][q * 8];
        const half8 bf1 = *(const half8*)&hlds[rb][n][32 + q * 8];

        // Next step's x: branchless on ALL waves (broadcast read, kills the
        // wave-3 branch skew; only xlane lanes consume it).
        const float xnext = xs[(t + 1) & (TSZ - 1)][ln & 7];

        floatx4 acc[4];
#pragma unroll
        for (int g = 0; g < 4; ++g) {
            acc[g] = __builtin_amdgcn_mfma_f32_16x16x32_f16(af[g][0], bf0, zero4,  0, 0, 0);
            acc[g] = __builtin_amdgcn_mfma_f32_16x16x32_f16(af[g][1], bf1, acc[g], 0, 0, 0);
        }

        // In-register selection (mirror cols): hi lanes use their own r=2,3.
        float pa[4], pb[4];
#pragma unroll
        for (int g = 0; g < 4; ++g) {
            pa[g] = hi ? acc[g][2] : acc[g][0];
            pb[g] = hi ? acc[g][3] : acc[g][1];
        }

        _Float16* const hw = wb ? hwp1 : hwp0;

        // --- cell 0: complete chain, then write immediately (b16 stores
        //     issue early; their latency hides under cell 1's trans chain).
        {
            const float i0 = sig_y (pa[0]);
            const float f0 = sig_y (pa[1]);
            const float g0 = tanh_y(pa[2]);
            const float o0 = sig_y (pa[3]);
            c0 = fmaf(f0, c0, i0 * g0);
            float h0 = o0 * tanh_y(c0 * 2.88539008f);
            if (xlane) h0 = 1.0f;                 // unit 50: augmentation const
            const _Float16 hh0 = (_Float16)h0;
            hw[0]        = hh0;                   // row nb
            hw[8 * KPAD] = hh0;                   // mirror row nb+8
        }
        // --- cell 1 ---
        {
            const float i1 = sig_y (pb[0]);
            const float f1 = sig_y (pb[1]);
            const float g1 = tanh_y(pb[2]);
            const float o1 = sig_y (pb[3]);
            c1 = fmaf(f1, c1, i1 * g1);
            float h1 = o1 * tanh_y(c1 * 2.88539008f);
            if (xlane) h1 = xnext;                // unit 51: x_{t+1} augmentation
            const _Float16 hh1 = (_Float16)h1;
            hw[1]            = hh1;               // row nb
            hw[8 * KPAD + 1] = hh1;               // mirror row nb+8
        }
        __syncthreads();             // h(t) visible for next step's B-read
    }

    // --- epilogue: out[b0+n'] = b_lin + sum_u h_T[u]*W_lin[u]; TSZ even -> buf 0
    if (w == 0 && ln < NB) {
        float acc = b_lin[0];
        for (int u = 0; u < HSZ; ++u)
            acc = fmaf((float)hlds[0][ln][u], W_lin[u], acc);
        out[(size_t)b0 + ln] = acc;
    }
}

extern "C" void kernel_launch(void* const* d_in, const int* in_sizes, int n_in,
                              void* d_out, int out_size, void* d_ws, size_t ws_size,
                              hipStream_t stream) {
    const float* x     = (const float*)d_in[0];
    const float* W_ih  = (const float*)d_in[1];
    const float* W_hh  = (const float*)d_in[2];
    const float* b_ih  = (const float*)d_in[3];
    const float* b_hh  = (const float*)d_in[4];
    const float* W_lin = (const float*)d_in[5];
    const float* b_lin = (const float*)d_in[6];
    float* outp = (float*)d_out;

    const int B = in_sizes[0] / TSZ;   // 2048 -> 256 workgroups of 8 batches
    hipLaunchKernelGGL(lstm_trim, dim3(B / NB), dim3(256), 0, stream,
                       x, W_ih, W_hh, b_ih, b_hh, W_lin, b_lin, outp);
}

// Round 6
// 223.218 us; speedup vs baseline: 1.8366x; 1.0245x over previous
//
#include <hip/hip_runtime.h>

#define HSZ 50        // real hidden units
#define TSZ 512       // timesteps
#define NB  8         // batches per workgroup -> 256 wgs (1 per CU)
#define KPAD 72       // hlds row stride in f16 (144 B, 16B-aligned)

typedef _Float16 half8  __attribute__((ext_vector_type(8)));
typedef float   floatx4 __attribute__((ext_vector_type(4)));

#define L2E2  2.88539008f      // 2*log2(e)
#define NL2E4 5.77078016f      // 4*log2(e)

__device__ __forceinline__ float rcp1p(float e) {   // rcp(1+e)
    return __builtin_amdgcn_rcpf(1.0f + e);
}
__device__ __forceinline__ float ex2(float y) {
    return __builtin_amdgcn_exp2f(y);
}

// R15: pipe-overlap pass on R14 (845 cy/step). Counters showed MFMA pipe
// (127cy), VALU+trans (405cy) and latency (~300cy) are SERIALIZED: all 8
// MFMAs were issued before any activation started. This version interleaves
// per-gate: gate i/f extraction + exp2 issue while gate g/o MFMAs are still
// occupying the matrix pipe (separate pipes -> dual progress, hides ~60-90cy
// of trans issue). Also keeps the cell state in the scaled domain
// cs = 2*log2e*c: the g-gate tanh returns 2.885*tanh (constants folded into
// its fmaf) and tanh(c) = 1-2*rcp(1+exp2(cs)) -- the dependent mul on the
// per-step c->h chain disappears.
// Kept from R14/R11: K-augmentation (bias k=50, x_t k=51 -> zero C-input),
// x2 mirror cols (selection from own registers), pre-scaled A rows
// (exp2-ready MFMA output), per-cell early b16 h-writes, branchless xnext,
// 1 barrier/step, waves_per_eu(1,1).
__global__ __launch_bounds__(256) __attribute__((amdgpu_waves_per_eu(1, 1)))
void lstm_ovl(const float* __restrict__ x,
              const float* __restrict__ W_ih,
              const float* __restrict__ W_hh,
              const float* __restrict__ b_ih,
              const float* __restrict__ b_hh,
              const float* __restrict__ W_lin,
              const float* __restrict__ b_lin,
              float* __restrict__ out)
{
    __shared__ float xs[TSZ][NB];                         // x^T [t][n]  (16 KB)
    __shared__ __align__(16) _Float16 hlds[2][16][KPAD];  // aug-h^T dbuf (4.5 KB)

    const int tid = threadIdx.x;
    const int w   = tid >> 6;        // wave id 0..3 -> unit group [16w,16w+16)
    const int ln  = tid & 63;        // lane
    const int n   = ln & 15;         // MFMA column
    const int q   = ln >> 4;         // quad
    const int hi  = (n >> 3) & 1;    // 0: units 4q..4q+1, 1: units 4q+2..4q+3
    const int nb  = n & 7;           // real batch this lane activates
    const int b0  = blockIdx.x * NB;

    // --- stage x transposed: global [b][t] -> LDS [t][b] (coalesced) ---
    const float* xg = x + (size_t)b0 * TSZ;
    for (int i = tid; i < NB * TSZ; i += 256)
        xs[i & (TSZ - 1)][i >> 9] = xg[i];
    // --- init h buffers: zero except k==50 slot = 1.0 (both buffers) ---
    for (int i = tid; i < 2 * 16 * KPAD; i += 256)
        ((_Float16*)hlds)[i] = (i % KPAD == 50) ? (_Float16)1.0f : (_Float16)0.0f;

    // --- A fragments: lane holds A[m=16w+n][k=kt*32+q*8+j], augmented and
    //     pre-scaled: k<50 -> W_hh ; k==50 -> b_ih+b_hh ; k==51 -> W_ih.
    //     Row scale: gates i,f,o -> -log2e ; gate g -> +2*log2e.
    const int uA = 16 * w + n;
    half8 af[4][2];
#pragma unroll
    for (int g = 0; g < 4; ++g) {
        const float gs = (g == 2) ? 2.88539008f : -1.44269504f;
        const int row = g * HSZ + uA;
        const bool rok = (uA < HSZ);
#pragma unroll
        for (int kt = 0; kt < 2; ++kt) {
#pragma unroll
            for (int j = 0; j < 8; ++j) {
                const int k = kt * 32 + q * 8 + j;
                float v = 0.0f;
                if (rok) {
                    if (k < HSZ)      v = W_hh[row * HSZ + k];
                    else if (k == 50) v = b_ih[row] + b_hh[row];
                    else if (k == 51) v = W_ih[row];
                }
                af[g][kt][j] = (_Float16)(v * gs);
            }
        }
    }

    float c0 = 0.0f, c1 = 0.0f;      // SCALED cell states (2*log2e*c)
    __syncthreads();                 // xs + hlds base fill ready
    if (tid < 16)                    // x_0 into buffer 0's aug slot, both halves
        hlds[0][tid][51] = (_Float16)xs[0][tid & 7];
    __syncthreads();

    const floatx4 zero4 = {0.0f, 0.0f, 0.0f, 0.0f};
    // h destination: row nb (+ mirror nb+8), cols 16w+4q+2*hi .. +1
    const int kcol = 16 * w + 4 * q + 2 * hi;
    _Float16* const hwp0 = &hlds[0][nb][kcol];
    _Float16* const hwp1 = &hlds[1][nb][kcol];
    const bool xlane = (w == 3) && (q == 0) && (hi == 1);  // units 50,51

#pragma unroll 2
    for (int t = 0; t < TSZ; ++t) {
        const int rb = t & 1, wb = rb ^ 1;

        // B fragments: hlds[rb][n][k-contiguous]; cols 8..15 mirror cols 0..7
        const half8 bf0 = *(const half8*)&hlds[rb][n][q * 8];
        const half8 bf1 = *(const half8*)&hlds[rb][n][32 + q * 8];
        const float xnext = xs[(t + 1) & (TSZ - 1)][ln & 7];

        // --- per-gate interleave: MFMA pipe vs trans pipe overlap ---
        floatx4 a0 = __builtin_amdgcn_mfma_f32_16x16x32_f16(af[0][0], bf0, zero4, 0, 0, 0);
        floatx4 a1 = __builtin_amdgcn_mfma_f32_16x16x32_f16(af[1][0], bf0, zero4, 0, 0, 0);
        floatx4 a2 = __builtin_amdgcn_mfma_f32_16x16x32_f16(af[2][0], bf0, zero4, 0, 0, 0);
        floatx4 a3 = __builtin_amdgcn_mfma_f32_16x16x32_f16(af[3][0], bf0, zero4, 0, 0, 0);
        a0 = __builtin_amdgcn_mfma_f32_16x16x32_f16(af[0][1], bf1, a0, 0, 0, 0);
        a1 = __builtin_amdgcn_mfma_f32_16x16x32_f16(af[1][1], bf1, a1, 0, 0, 0);

        // gate i (a0): extract + exp2 while a2/a3 second halves issue
        const float pi_a = hi ? a0[2] : a0[0], pi_b = hi ? a0[3] : a0[1];
        const float ei_a = ex2(pi_a),          ei_b = ex2(pi_b);

        a2 = __builtin_amdgcn_mfma_f32_16x16x32_f16(af[2][1], bf1, a2, 0, 0, 0);

        const float pf_a = hi ? a1[2] : a1[0], pf_b = hi ? a1[3] : a1[1];
        const float ef_a = ex2(pf_a),          ef_b = ex2(pf_b);

        a3 = __builtin_amdgcn_mfma_f32_16x16x32_f16(af[3][1], bf1, a3, 0, 0, 0);

        const float pg_a = hi ? a2[2] : a2[0], pg_b = hi ? a2[3] : a2[1];
        const float eg_a = ex2(pg_a),          eg_b = ex2(pg_b);
        const float po_a = hi ? a3[2] : a3[0], po_b = hi ? a3[3] : a3[1];
        const float eo_a = ex2(po_a),          eo_b = ex2(po_b);

        // sigmoids / scaled tanh (g gate returns 2.885*tanh)
        const float i_a = rcp1p(ei_a), i_b = rcp1p(ei_b);
        const float f_a = rcp1p(ef_a), f_b = rcp1p(ef_b);
        const float g_a = fmaf(-NL2E4, rcp1p(eg_a), L2E2);
        const float g_b = fmaf(-NL2E4, rcp1p(eg_b), L2E2);
        const float o_a = rcp1p(eo_a), o_b = rcp1p(eo_b);

        _Float16* const hw = wb ? hwp1 : hwp0;

        // cell 0: cs-update, then h = o*(1 - 2*rcp(1+exp2(cs))); write early
        c0 = fmaf(f_a, c0, i_a * g_a);
        {
            float h0 = o_a * fmaf(-2.0f, rcp1p(ex2(c0)), 1.0f);
            if (xlane) h0 = 1.0f;                 // unit 50: augmentation const
            const _Float16 hh0 = (_Float16)h0;
            hw[0]        = hh0;                   // row nb
            hw[8 * KPAD] = hh0;                   // mirror row nb+8
        }
        // cell 1
        c1 = fmaf(f_b, c1, i_b * g_b);
        {
            float h1 = o_b * fmaf(-2.0f, rcp1p(ex2(c1)), 1.0f);
            if (xlane) h1 = xnext;                // unit 51: x_{t+1} augmentation
            const _Float16 hh1 = (_Float16)h1;
            hw[1]            = hh1;               // row nb
            hw[8 * KPAD + 1] = hh1;               // mirror row nb+8
        }
        __syncthreads();             // h(t) visible for next step's B-read
    }

    // --- epilogue: out[b0+n'] = b_lin + sum_u h_T[u]*W_lin[u]; TSZ even -> buf 0
    if (w == 0 && ln < NB) {
        float acc = b_lin[0];
        for (int u = 0; u < HSZ; ++u)
            acc = fmaf((float)hlds[0][ln][u], W_lin[u], acc);
        out[(size_t)b0 + ln] = acc;
    }
}

extern "C" void kernel_launch(void* const* d_in, const int* in_sizes, int n_in,
                              void* d_out, int out_size, void* d_ws, size_t ws_size,
                              hipStream_t stream) {
    const float* x     = (const float*)d_in[0];
    const float* W_ih  = (const float*)d_in[1];
    const float* W_hh  = (const float*)d_in[2];
    const float* b_ih  = (const float*)d_in[3];
    const float* b_hh  = (const float*)d_in[4];
    const float* W_lin = (const float*)d_in[5];
    const float* b_lin = (const float*)d_in[6];
    float* outp = (float*)d_out;

    const int B = in_sizes[0] / TSZ;   // 2048 -> 256 workgroups of 8 batches
    hipLaunchKernelGGL(lstm_ovl, dim3(B / NB), dim3(256), 0, stream,
                       x, W_ih, W_hh, b_ih, b_hh, W_lin, b_lin, outp);
}

// Round 7
// 218.493 us; speedup vs baseline: 1.8763x; 1.0216x over previous
//
#include <hip/hip_runtime.h>

#define HSZ 50        // real hidden units
#define TSZ 512       // timesteps
#define NB  8         // batches per workgroup -> 256 wgs (1 per CU)
#define KPAD 72       // hlds row stride in f16 (144 B, 16B-aligned)

typedef _Float16 half8  __attribute__((ext_vector_type(8)));
typedef _Float16 half2v __attribute__((ext_vector_type(2)));
typedef float   floatx4 __attribute__((ext_vector_type(4)));

#define L2E2  2.88539008f      // 2*log2(e)

__device__ __forceinline__ float rcp1p(float e) {   // rcp(1+e)
    return __builtin_amdgcn_rcpf(1.0f + e);
}
__device__ __forceinline__ float ex2(float y) {
    return __builtin_amdgcn_exp2f(y);
}

// R16: issue-count surgery on R15 (810 cy/step; VALU+trans ~380cy is the
// largest pipe consumer).
// (1) rcp fusion: i*g = 2.885*(eg-1)*rcp((1+ei)(1+eg)) and
//     h = (ec-1)*rcp((1+eo)(1+ec)) -- 5 rcp/cell -> 3 rcp/cell (-4 trans
//     ops/lane/step). NaN needs exp2 overflow (|preact|>=44 or c_s>=128;
//     actual preacts ~+-3); c_s additionally clamped to 100 (1 v_min).
// (2) gate order i,g,f,o: longest post-chain (ig fusion) starts 2 MFMAs
//     early and hides under f/o matrix-pipe time; o (one mul into h) last.
// (3) packed b32 h-writes: 2 ds_write_b32 instead of 4 ds_write_b16
//     (same last-write time, fewer DS issues).
// Kept: K-augmentation (bias k=50, x_t k=51 -> zero C-input), x2 mirror
// cols (selection from own registers), pre-scaled A rows (exp2-ready MFMA
// output), scaled-c domain, branchless xnext, 1 barrier/step,
// waves_per_eu(1,1).
__global__ __launch_bounds__(256) __attribute__((amdgpu_waves_per_eu(1, 1)))
void lstm_fus(const float* __restrict__ x,
              const float* __restrict__ W_ih,
              const float* __restrict__ W_hh,
              const float* __restrict__ b_ih,
              const float* __restrict__ b_hh,
              const float* __restrict__ W_lin,
              const float* __restrict__ b_lin,
              float* __restrict__ out)
{
    __shared__ float xs[TSZ][NB];                         // x^T [t][n]  (16 KB)
    __shared__ __align__(16) _Float16 hlds[2][16][KPAD];  // aug-h^T dbuf (4.5 KB)

    const int tid = threadIdx.x;
    const int w   = tid >> 6;        // wave id 0..3 -> unit group [16w,16w+16)
    const int ln  = tid & 63;        // lane
    const int n   = ln & 15;         // MFMA column
    const int q   = ln >> 4;         // quad
    const int hi  = (n >> 3) & 1;    // 0: units 4q..4q+1, 1: units 4q+2..4q+3
    const int nb  = n & 7;           // real batch this lane activates
    const int b0  = blockIdx.x * NB;

    // --- stage x transposed: global [b][t] -> LDS [t][b] (coalesced) ---
    const float* xg = x + (size_t)b0 * TSZ;
    for (int i = tid; i < NB * TSZ; i += 256)
        xs[i & (TSZ - 1)][i >> 9] = xg[i];
    // --- init h buffers: zero except k==50 slot = 1.0 (both buffers) ---
    for (int i = tid; i < 2 * 16 * KPAD; i += 256)
        ((_Float16*)hlds)[i] = (i % KPAD == 50) ? (_Float16)1.0f : (_Float16)0.0f;

    // --- A fragments: lane holds A[m=16w+n][k=kt*32+q*8+j], augmented and
    //     pre-scaled: k<50 -> W_hh ; k==50 -> b_ih+b_hh ; k==51 -> W_ih.
    //     Row scale: gates i,f,o -> -log2e ; gate g -> +2*log2e.
    const int uA = 16 * w + n;
    half8 af[4][2];
#pragma unroll
    for (int g = 0; g < 4; ++g) {
        const float gs = (g == 2) ? 2.88539008f : -1.44269504f;
        const int row = g * HSZ + uA;
        const bool rok = (uA < HSZ);
#pragma unroll
        for (int kt = 0; kt < 2; ++kt) {
#pragma unroll
            for (int j = 0; j < 8; ++j) {
                const int k = kt * 32 + q * 8 + j;
                float v = 0.0f;
                if (rok) {
                    if (k < HSZ)      v = W_hh[row * HSZ + k];
                    else if (k == 50) v = b_ih[row] + b_hh[row];
                    else if (k == 51) v = W_ih[row];
                }
                af[g][kt][j] = (_Float16)(v * gs);
            }
        }
    }

    float c0 = 0.0f, c1 = 0.0f;      // SCALED cell states (2*log2e*c)
    __syncthreads();                 // xs + hlds base fill ready
    if (tid < 16)                    // x_0 into buffer 0's aug slot, both halves
        hlds[0][tid][51] = (_Float16)xs[0][tid & 7];
    __syncthreads();

    const floatx4 zero4 = {0.0f, 0.0f, 0.0f, 0.0f};
    // h destination: row nb (+ mirror nb+8), cols 16w+4q+2*hi .. +1
    const int kcol = 16 * w + 4 * q + 2 * hi;
    _Float16* const hwp0 = &hlds[0][nb][kcol];
    _Float16* const hwp1 = &hlds[1][nb][kcol];
    const bool xlane = (w == 3) && (q == 0) && (hi == 1);  // units 50,51

#pragma unroll 2
    for (int t = 0; t < TSZ; ++t) {
        const int rb = t & 1, wb = rb ^ 1;

        // B fragments: hlds[rb][n][k-contiguous]; cols 8..15 mirror cols 0..7
        const half8 bf0 = *(const half8*)&hlds[rb][n][q * 8];
        const half8 bf1 = *(const half8*)&hlds[rb][n][32 + q * 8];
        const float xnext = xs[(t + 1) & (TSZ - 1)][ln & 7];

        // --- MFMA issue order i, g, f, o; extraction interleaved so the
        //     longest post-chain (ig fusion) starts while f/o MFMAs run.
        floatx4 ai = __builtin_amdgcn_mfma_f32_16x16x32_f16(af[0][0], bf0, zero4, 0, 0, 0);
        floatx4 ag = __builtin_amdgcn_mfma_f32_16x16x32_f16(af[2][0], bf0, zero4, 0, 0, 0);
        floatx4 afr= __builtin_amdgcn_mfma_f32_16x16x32_f16(af[1][0], bf0, zero4, 0, 0, 0);
        floatx4 ao = __builtin_amdgcn_mfma_f32_16x16x32_f16(af[3][0], bf0, zero4, 0, 0, 0);
        ai = __builtin_amdgcn_mfma_f32_16x16x32_f16(af[0][1], bf1, ai, 0, 0, 0);
        ag = __builtin_amdgcn_mfma_f32_16x16x32_f16(af[2][1], bf1, ag, 0, 0, 0);

        const float pi_a = hi ? ai[2] : ai[0], pi_b = hi ? ai[3] : ai[1];
        const float ei_a = ex2(pi_a),          ei_b = ex2(pi_b);

        afr = __builtin_amdgcn_mfma_f32_16x16x32_f16(af[1][1], bf1, afr, 0, 0, 0);

        const float pg_a = hi ? ag[2] : ag[0], pg_b = hi ? ag[3] : ag[1];
        const float eg_a = ex2(pg_a),          eg_b = ex2(pg_b);

        ao = __builtin_amdgcn_mfma_f32_16x16x32_f16(af[3][1], bf1, ao, 0, 0, 0);

        // fused i*g (scaled domain): 2.885*(eg-1)*rcp((1+ei)(1+eg))
        const float ig_a = L2E2 * (eg_a - 1.0f) *
                           __builtin_amdgcn_rcpf((1.0f + ei_a) * (1.0f + eg_a));
        const float ig_b = L2E2 * (eg_b - 1.0f) *
                           __builtin_amdgcn_rcpf((1.0f + ei_b) * (1.0f + eg_b));

        const float pf_a = hi ? afr[2] : afr[0], pf_b = hi ? afr[3] : afr[1];
        const float ef_a = ex2(pf_a),            ef_b = ex2(pf_b);
        const float f_a  = rcp1p(ef_a),          f_b  = rcp1p(ef_b);

        const float po_a = hi ? ao[2] : ao[0], po_b = hi ? ao[3] : ao[1];
        const float eo_a = ex2(po_a),          eo_b = ex2(po_b);

        // scaled-c update (clamped: exp2 overflow-proof) and fused h
        c0 = fminf(fmaf(f_a, c0, ig_a), 100.0f);
        c1 = fminf(fmaf(f_b, c1, ig_b), 100.0f);
        const float ec_a = ex2(c0), ec_b = ex2(c1);
        float h0 = (ec_a - 1.0f) *
                   __builtin_amdgcn_rcpf((1.0f + eo_a) * (1.0f + ec_a));
        float h1 = (ec_b - 1.0f) *
                   __builtin_amdgcn_rcpf((1.0f + eo_b) * (1.0f + ec_b));
        if (xlane) { h0 = 1.0f; h1 = xnext; }

        _Float16* const hw = wb ? hwp1 : hwp0;
        const half2v hv = {(_Float16)h0, (_Float16)h1};
        *(half2v*)hw = hv;                       // row nb (cols kcol, kcol+1)
        *(half2v*)(hw + 8 * KPAD) = hv;          // mirror row nb+8
        __syncthreads();             // h(t) visible for next step's B-read
    }

    // --- epilogue: out[b0+n'] = b_lin + sum_u h_T[u]*W_lin[u]; TSZ even -> buf 0
    if (w == 0 && ln < NB) {
        float acc = b_lin[0];
        for (int u = 0; u < HSZ; ++u)
            acc = fmaf((float)hlds[0][ln][u], W_lin[u], acc);
        out[(size_t)b0 + ln] = acc;
    }
}

extern "C" void kernel_launch(void* const* d_in, const int* in_sizes, int n_in,
                              void* d_out, int out_size, void* d_ws, size_t ws_size,
                              hipStream_t stream) {
    const float* x     = (const float*)d_in[0];
    const float* W_ih  = (const float*)d_in[1];
    const float* W_hh  = (const float*)d_in[2];
    const float* b_ih  = (const float*)d_in[3];
    const float* b_hh  = (const float*)d_in[4];
    const float* W_lin = (const float*)d_in[5];
    const float* b_lin = (const float*)d_in[6];
    float* outp = (float*)d_out;

    const int B = in_sizes[0] / TSZ;   // 2048 -> 256 workgroups of 8 batches
    hipLaunchKernelGGL(lstm_fus, dim3(B / NB), dim3(256), 0, stream,
                       x, W_ih, W_hh, b_ih, b_hh, W_lin, b_lin, outp);
}